// Round 2
// baseline (1294.676 us; speedup 1.0000x reference)
//
#include <hip/hip_runtime.h>
#include <stdint.h>

#define HD   128
#define ED   100
#define VD   1000
#define FDV  512
#define NS   512
#define TT   64
#define MT   (NS*TT)   // 32768

typedef __attribute__((ext_vector_type(8))) short  short8;
typedef __attribute__((ext_vector_type(4))) float  f32x4;

__device__ __forceinline__ float blo(uint32_t u){ return __uint_as_float(u << 16); }
__device__ __forceinline__ float bhi(uint32_t u){ return __uint_as_float(u & 0xffff0000u); }
__device__ __forceinline__ uint16_t f2bf(float f){
  uint32_t x = __float_as_uint(f);
  return (uint16_t)((x + 0x7fffu + ((x >> 16) & 1u)) >> 16);
}
__device__ __forceinline__ float sigf(float x){ return 1.f/(1.f+__expf(-x)); }

// ---------------- weight/emb conversion (f32 -> bf16, K-padded) ----------------
struct ConvJob { const float* s; uint16_t* d; int R, C, Cp; };
struct ConvJobs { ConvJob j[11]; };

__global__ void k_convert(ConvJobs jobs){
  int stride = gridDim.x * blockDim.x;
  int tid0 = blockIdx.x * blockDim.x + threadIdx.x;
  for (int ji = 0; ji < 11; ++ji){
    const ConvJob jb = jobs.j[ji];
    int total = jb.R * jb.Cp;
    for (int i = tid0; i < total; i += stride){
      int r = i / jb.Cp, c = i - r*jb.Cp;
      float v = (c < jb.C) ? jb.s[(size_t)r*jb.C + c] : 0.f;
      jb.d[i] = f2bf(v);
    }
  }
}

// ---------------- embedding gather: tok[m] -> bf16 padded rows [MT][128] ----------------
__global__ void k_gather(const uint16_t* __restrict__ embP, const int* __restrict__ tok,
                         uint16_t* __restrict__ out){
  int i = blockIdx.x * blockDim.x + threadIdx.x;   // one uint4 (8 bf16) per thread
  if (i >= MT*16) return;
  int m = i >> 4, c8 = i & 15;
  int v = tok[m];
  ((uint4*)(out + (size_t)m*128))[c8] = ((const uint4*)(embP + (size_t)v*128))[c8];
}

// ---------------- bf16 MFMA GEMM: C[M,N] = A[M,K] @ W[N,K]^T + bias ----------------
// MODE 0: f32 out; 1: bf16 out; 2: f32 out with t>=lens[n] row masking
template<int MODE>
__global__ __launch_bounds__(256) void k_gemm(
    const uint16_t* __restrict__ A, const uint16_t* __restrict__ W,
    const float* __restrict__ bias, void* __restrict__ out,
    int N, int K, const int* __restrict__ lens)
{
  __shared__ __align__(16) uint16_t lsA[128][40];  // +4 bf16 pad
  __shared__ __align__(16) uint16_t lsB[128][40];
  const int tid = threadIdx.x;
  const int m0 = blockIdx.x * 128, n0 = blockIdx.y * 128;
  const int l = tid & 63, w = tid >> 6;
  const int wm = (w >> 1) * 64, wn = (w & 1) * 64;
  const int fr = l & 15, fo = (l >> 4) * 8;
  f32x4 acc[4][4] = {};
  for (int kt = 0; kt < K; kt += 32) {
    #pragma unroll
    for (int u = 0; u < 2; ++u) {
      int c = tid + u * 256;
      int row = c >> 2, ko = (c & 3) << 3;
      uint4 av = *(const uint4*)(A + (size_t)(m0 + row) * K + kt + ko);
      *(uint4*)(&lsA[row][ko]) = av;
      int nr = n0 + row;
      uint4 bv = make_uint4(0u,0u,0u,0u);
      if (nr < N) bv = *(const uint4*)(W + (size_t)nr * K + kt + ko);
      *(uint4*)(&lsB[row][ko]) = bv;
    }
    __syncthreads();
    short8 af[4], bfv[4];
    #pragma unroll
    for (int i = 0; i < 4; ++i) af[i]  = *(const short8*)(&lsA[wm + i*16 + fr][fo]);
    #pragma unroll
    for (int j = 0; j < 4; ++j) bfv[j] = *(const short8*)(&lsB[wn + j*16 + fr][fo]);
    #pragma unroll
    for (int i = 0; i < 4; ++i)
      #pragma unroll
      for (int j = 0; j < 4; ++j)
        acc[i][j] = __builtin_amdgcn_mfma_f32_16x16x32_bf16(af[i], bfv[j], acc[i][j], 0, 0, 0);
    __syncthreads();
  }
  const int r0 = (l >> 4) * 4, cc = l & 15;
  #pragma unroll
  for (int j = 0; j < 4; ++j) {
    int col = n0 + wn + j*16 + cc;
    if (col >= N) continue;
    float bv = bias[col];
    #pragma unroll
    for (int i = 0; i < 4; ++i) {
      #pragma unroll
      for (int r = 0; r < 4; ++r) {
        int row = m0 + wm + i*16 + r0 + r;
        float v = acc[i][j][r] + bv;
        if (MODE == 1) {
          ((uint16_t*)out)[(size_t)row * N + col] = f2bf(v);
        } else if (MODE == 2) {
          int t = row & 63, n = row >> 6;
          if (t >= lens[n]) v = 0.f;
          ((float*)out)[(size_t)row * N + col] = v;
        } else {
          ((float*)out)[(size_t)row * N + col] = v;
        }
      }
    }
  }
}

// ---------------- per-sample LSTM recurrence (Wih*x + b precomputed in X) ----------------
// block = sample n, 512 threads; thread j owns Whh row j (bf16 in VGPRs).
__global__ __launch_bounds__(512) void k_lstm(
    const uint16_t* __restrict__ X,      // [NS*TT][512] bf16 = x@Wih^T + b
    const uint16_t* __restrict__ Whh,    // [512][128] bf16
    const float* __restrict__ h0i, const float* __restrict__ c0i,  // [NS][128] or null
    uint16_t* __restrict__ hout,         // [NS*TT][128] bf16
    float* __restrict__ hfin, float* __restrict__ cfin)            // [NS][128] or null
{
  __shared__ __align__(16) float hs[128];
  __shared__ float zs[512];
  const int n = blockIdx.x, j = threadIdx.x;
  uint4 wr[16];
  {
    const uint4* wp = (const uint4*)(Whh + (size_t)j * 128);
    #pragma unroll
    for (int i = 0; i < 16; ++i) wr[i] = wp[i];
  }
  float c = 0.f;
  if (j < 128) {
    hs[j] = h0i ? h0i[(size_t)n*128 + j] : 0.f;
    c     = c0i ? c0i[(size_t)n*128 + j] : 0.f;
  }
  __syncthreads();
  for (int t = 0; t < TT; ++t) {
    float x = blo((uint32_t)X[((size_t)n*TT + t)*512 + j]);  // bf16 -> f32
    float a0 = 0.f, a1 = 0.f, a2 = 0.f, a3 = 0.f;
    const float4* h4 = (const float4*)hs;
    #pragma unroll
    for (int k = 0; k < 16; ++k) {
      float4 h0v = h4[2*k], h1v = h4[2*k+1];
      uint4 wv = wr[k];
      a0 += h0v.x * blo(wv.x); a1 += h0v.y * bhi(wv.x);
      a2 += h0v.z * blo(wv.y); a3 += h0v.w * bhi(wv.y);
      a0 += h1v.x * blo(wv.z); a1 += h1v.y * bhi(wv.z);
      a2 += h1v.z * blo(wv.w); a3 += h1v.w * bhi(wv.w);
    }
    zs[j] = x + ((a0 + a1) + (a2 + a3));
    __syncthreads();
    if (j < 128) {
      float ig = sigf(zs[j]);
      float fg = sigf(zs[j + 128]);
      float gg = tanhf(zs[j + 256]);
      float og = sigf(zs[j + 384]);
      c = fg * c + ig * gg;
      float h = og * tanhf(c);
      hs[j] = h;
      hout[((size_t)n*TT + t)*HD + j] = f2bf(h);
    }
    __syncthreads();
  }
  if (j < 128) {
    if (hfin) hfin[(size_t)n*128 + j] = hs[j];
    if (cfin) cfin[(size_t)n*128 + j] = c;
  }
}

// ---------------- attention: per question n, keys staged in LDS ----------------
__global__ __launch_bounds__(256) void k_attn(
    const float* __restrict__ keys,     // [MT][128] f32
    const uint16_t* __restrict__ h1,    // [MT][128] bf16 (decoder layer-1 h)
    uint16_t* __restrict__ feat)        // [MT][896], writes cols 128..255 (ctx)
{
  __shared__ float ks[64][129];
  __shared__ float ps[4][64];
  const int n = blockIdx.x;
  for (int i = threadIdx.x; i < 64*128; i += 256)
    ks[i >> 7][i & 127] = keys[(size_t)n*8192 + i];
  __syncthreads();
  const int w = threadIdx.x >> 6, l = threadIdx.x & 63;
  for (int tt = 0; tt < 16; ++tt) {
    const int t = tt*4 + w;
    const int m = n*64 + t;
    const uint4* hp = (const uint4*)(h1 + (size_t)m*128);
    float s = 0.f;
    #pragma unroll
    for (int k = 0; k < 16; ++k) {
      uint4 hv = hp[k];
      s += ks[l][8*k+0]*blo(hv.x) + ks[l][8*k+1]*bhi(hv.x)
         + ks[l][8*k+2]*blo(hv.y) + ks[l][8*k+3]*bhi(hv.y)
         + ks[l][8*k+4]*blo(hv.z) + ks[l][8*k+5]*bhi(hv.z)
         + ks[l][8*k+6]*blo(hv.w) + ks[l][8*k+7]*bhi(hv.w);
    }
    float mx = s;
    #pragma unroll
    for (int o = 32; o; o >>= 1) mx = fmaxf(mx, __shfl_xor(mx, o));
    float p = __expf(s - mx);
    float sm = p;
    #pragma unroll
    for (int o = 32; o; o >>= 1) sm += __shfl_xor(sm, o);
    p /= sm;
    ps[w][l] = p;
    float c0 = 0.f, c1 = 0.f;
    #pragma unroll
    for (int q = 0; q < 64; ++q) {
      float pq = ps[w][q];
      c0 += pq * ks[q][l];
      c1 += pq * ks[q][l + 64];
    }
    feat[(size_t)m*896 + 128 + l] = f2bf(c0);
    feat[(size_t)m*896 + 192 + l] = f2bf(c1);
  }
}

// ---------------- feat assembly: cols 0..127 h1, 256..383 hist, 384..895 img ----------------
__global__ void k_feat(const uint16_t* __restrict__ h1, const float* __restrict__ img,
                       uint16_t* __restrict__ feat){
  int i = blockIdx.x * blockDim.x + threadIdx.x;    // one 8-elem chunk
  if (i >= MT*96) return;
  int m = i / 96, c8 = i - m*96;
  int c = c8 * 8;
  if (c < 128) {
    uint4 v = ((const uint4*)(h1 + (size_t)m*128))[c8];
    *(uint4*)(feat + (size_t)m*896 + c) = v;
  } else if (c < 256) {
    int n = m >> 6;
    uint4 v = make_uint4(0u,0u,0u,0u);
    if (n > 0) v = ((const uint4*)(h1 + ((size_t)(n-1)*64 + 63)*128))[c8 - 16];
    *(uint4*)(feat + (size_t)m*896 + 128 + c) = v;   // col = c+128 in [256,384)
  } else {
    const float4* ip = (const float4*)img;
    float4 f0 = ip[(c - 256) >> 2], f1 = ip[((c - 256) >> 2) + 1];
    uint16_t o[8];
    o[0]=f2bf(f0.x); o[1]=f2bf(f0.y); o[2]=f2bf(f0.z); o[3]=f2bf(f0.w);
    o[4]=f2bf(f1.x); o[5]=f2bf(f1.y); o[6]=f2bf(f1.z); o[7]=f2bf(f1.w);
    *(uint4*)(feat + (size_t)m*896 + 128 + c) = *(uint4*)o;  // col = c+128 in [384,896)
  }
}

extern "C" void kernel_launch(void* const* d_in, const int* in_sizes, int n_in,
                              void* d_out, int out_size, void* d_ws, size_t ws_size,
                              hipStream_t stream) {
  const int*   questions = (const int*)d_in[0];
  const int*   answers   = (const int*)d_in[1];
  const int*   lens      = (const int*)d_in[2];
  const float* img       = (const float*)d_in[3];
  const float* emb       = (const float*)d_in[4];
  const float* eWih0 = (const float*)d_in[5],  *eWhh0 = (const float*)d_in[6],  *eB0 = (const float*)d_in[7];
  const float* eWih1 = (const float*)d_in[8],  *eWhh1 = (const float*)d_in[9],  *eB1 = (const float*)d_in[10];
  const float* dWih0 = (const float*)d_in[11], *dWhh0 = (const float*)d_in[12], *dB0 = (const float*)d_in[13];
  const float* dWih1 = (const float*)d_in[14], *dWhh1 = (const float*)d_in[15], *dB1 = (const float*)d_in[16];
  const float* Wk   = (const float*)d_in[17], *bk   = (const float*)d_in[18];
  const float* Wout = (const float*)d_in[19], *bout = (const float*)d_in[20];

  char* ws = (char*)d_ws;
  size_t off = 0;
  auto alloc = [&](size_t n)->char* {
    char* p = ws + off; off += (n + 255) & ~(size_t)255; return p;
  };
  uint16_t* embP  = (uint16_t*)alloc((size_t)VD*128*2);
  uint16_t* wih0e = (uint16_t*)alloc(512*128*2);
  uint16_t* whh0e = (uint16_t*)alloc(512*128*2);
  uint16_t* wih1e = (uint16_t*)alloc(512*128*2);
  uint16_t* whh1e = (uint16_t*)alloc(512*128*2);
  uint16_t* wih0d = (uint16_t*)alloc(512*128*2);
  uint16_t* whh0d = (uint16_t*)alloc(512*128*2);
  uint16_t* wih1d = (uint16_t*)alloc(512*128*2);
  uint16_t* whh1d = (uint16_t*)alloc(512*128*2);
  uint16_t* wkb   = (uint16_t*)alloc(128*128*2);
  uint16_t* woutb = (uint16_t*)alloc((size_t)VD*896*2);
  uint16_t* embBuf= (uint16_t*)alloc((size_t)MT*128*2);
  uint16_t* Xbuf  = (uint16_t*)alloc((size_t)MT*512*2);
  uint16_t* hA    = (uint16_t*)alloc((size_t)MT*128*2);
  uint16_t* h1b   = (uint16_t*)alloc((size_t)MT*128*2);
  float*    keysf = (float*)   alloc((size_t)MT*128*4);
  uint16_t* feat  = (uint16_t*)alloc((size_t)MT*896*2);
  float* eh0 = (float*)alloc(NS*128*4);
  float* ec0 = (float*)alloc(NS*128*4);
  float* eh1 = (float*)alloc(NS*128*4);
  float* ec1 = (float*)alloc(NS*128*4);
  if (off > ws_size) return;  // workspace too small; fail visibly

  // 1) convert all weights/emb to bf16 (padded K where needed)
  ConvJobs jobs;
  jobs.j[0]  = {emb,   embP,  VD, ED, 128};
  jobs.j[1]  = {eWih0, wih0e, 512, ED, 128};
  jobs.j[2]  = {eWhh0, whh0e, 512, 128, 128};
  jobs.j[3]  = {eWih1, wih1e, 512, 128, 128};
  jobs.j[4]  = {eWhh1, whh1e, 512, 128, 128};
  jobs.j[5]  = {dWih0, wih0d, 512, ED, 128};
  jobs.j[6]  = {dWhh0, whh0d, 512, 128, 128};
  jobs.j[7]  = {dWih1, wih1d, 512, 128, 128};
  jobs.j[8]  = {dWhh1, whh1d, 512, 128, 128};
  jobs.j[9]  = {Wk,    wkb,   128, 128, 128};
  jobs.j[10] = {Wout,  woutb, VD, 896, 896};
  hipLaunchKernelGGL(k_convert, dim3(1024), dim3(256), 0, stream, jobs);

  // ---- encoder ----
  hipLaunchKernelGGL(k_gather, dim3(MT*16/256), dim3(256), 0, stream, embP, questions, embBuf);
  hipLaunchKernelGGL(k_gemm<1>, dim3(MT/128, 4), dim3(256), 0, stream, embBuf, wih0e, eB0, Xbuf, 512, 128, nullptr);
  hipLaunchKernelGGL(k_lstm, dim3(NS), dim3(512), 0, stream, Xbuf, whh0e, (const float*)nullptr, (const float*)nullptr, hA, eh0, ec0);
  hipLaunchKernelGGL(k_gemm<1>, dim3(MT/128, 4), dim3(256), 0, stream, hA, wih1e, eB1, Xbuf, 512, 128, nullptr);
  hipLaunchKernelGGL(k_lstm, dim3(NS), dim3(512), 0, stream, Xbuf, whh1e, (const float*)nullptr, (const float*)nullptr, h1b, eh1, ec1);
  hipLaunchKernelGGL(k_gemm<0>, dim3(MT/128, 1), dim3(256), 0, stream, h1b, wkb, bk, keysf, 128, 128, nullptr);

  // ---- decoder (parallel across questions; history only affects logits) ----
  hipLaunchKernelGGL(k_gather, dim3(MT*16/256), dim3(256), 0, stream, embP, answers, embBuf);
  hipLaunchKernelGGL(k_gemm<1>, dim3(MT/128, 4), dim3(256), 0, stream, embBuf, wih0d, dB0, Xbuf, 512, 128, nullptr);
  hipLaunchKernelGGL(k_lstm, dim3(NS), dim3(512), 0, stream, Xbuf, whh0d, eh0, ec0, hA, (float*)nullptr, (float*)nullptr);
  hipLaunchKernelGGL(k_gemm<1>, dim3(MT/128, 4), dim3(256), 0, stream, hA, wih1d, dB1, Xbuf, 512, 128, nullptr);
  hipLaunchKernelGGL(k_lstm, dim3(NS), dim3(512), 0, stream, Xbuf, whh1d, eh1, ec1, h1b, (float*)nullptr, (float*)nullptr);

  // ---- attention + feat assembly + output projection ----
  hipLaunchKernelGGL(k_attn, dim3(NS), dim3(256), 0, stream, keysf, h1b, feat);
  hipLaunchKernelGGL(k_feat, dim3((MT*96+255)/256), dim3(256), 0, stream, h1b, img, feat);
  hipLaunchKernelGGL(k_gemm<2>, dim3(MT/128, 8), dim3(256), 0, stream, feat, woutb, bout, d_out, VD, 896, lens);
}

// Round 3
// 931.706 us; speedup vs baseline: 1.3896x; 1.3896x over previous
//
#include <hip/hip_runtime.h>
#include <stdint.h>

#define HD   128
#define ED   100
#define VD   1000
#define FDV  512
#define NS   512
#define TT   64
#define MT   (NS*TT)   // 32768

typedef __attribute__((ext_vector_type(8))) short  short8;
typedef __attribute__((ext_vector_type(4))) float  f32x4;

__device__ __forceinline__ float blo(uint32_t u){ return __uint_as_float(u << 16); }
__device__ __forceinline__ float bhi(uint32_t u){ return __uint_as_float(u & 0xffff0000u); }
__device__ __forceinline__ uint16_t f2bf(float f){
  uint32_t x = __float_as_uint(f);
  return (uint16_t)((x + 0x7fffu + ((x >> 16) & 1u)) >> 16);
}
__device__ __forceinline__ float sigf(float x){ return 1.f/(1.f+__expf(-x)); }
__device__ __forceinline__ float ftanh(float x){
  float ax = fabsf(x);
  float e = __expf(-2.f*ax);
  float t = (1.f - e) / (1.f + e);
  return copysignf(t, x);
}

// ---------------- weight/emb conversion (f32 -> bf16, K-padded) ----------------
struct ConvJob { const float* s; uint16_t* d; int R, C, Cp; };
struct ConvJobs { ConvJob j[11]; };

__global__ void k_convert(ConvJobs jobs){
  int stride = gridDim.x * blockDim.x;
  int tid0 = blockIdx.x * blockDim.x + threadIdx.x;
  for (int ji = 0; ji < 11; ++ji){
    const ConvJob jb = jobs.j[ji];
    int total = jb.R * jb.Cp;
    for (int i = tid0; i < total; i += stride){
      int r = i / jb.Cp, c = i - r*jb.Cp;
      float v = (c < jb.C) ? jb.s[(size_t)r*jb.C + c] : 0.f;
      jb.d[i] = f2bf(v);
    }
  }
}

// ---------------- embedding gather: tok[m] -> bf16 padded rows [MT][128] ----------------
__global__ void k_gather(const uint16_t* __restrict__ embP, const int* __restrict__ tok,
                         uint16_t* __restrict__ out){
  int i = blockIdx.x * blockDim.x + threadIdx.x;   // one uint4 (8 bf16) per thread
  if (i >= MT*16) return;
  int m = i >> 4, c8 = i & 15;
  int v = tok[m];
  ((uint4*)(out + (size_t)m*128))[c8] = ((const uint4*)(embP + (size_t)v*128))[c8];
}

// ---------------- bf16 MFMA GEMM: C[M,N] = A[M,K] @ W[N,K]^T + bias ----------------
// MODE 0: f32 out; 1: bf16 out; 2: f32 out with t>=lens[n] row masking
template<int MODE>
__global__ __launch_bounds__(256) void k_gemm(
    const uint16_t* __restrict__ A, const uint16_t* __restrict__ W,
    const float* __restrict__ bias, void* __restrict__ out,
    int N, int K, const int* __restrict__ lens)
{
  __shared__ __align__(16) uint16_t lsA[128][40];  // +4 bf16 pad
  __shared__ __align__(16) uint16_t lsB[128][40];
  const int tid = threadIdx.x;
  const int m0 = blockIdx.x * 128, n0 = blockIdx.y * 128;
  const int l = tid & 63, w = tid >> 6;
  const int wm = (w >> 1) * 64, wn = (w & 1) * 64;
  const int fr = l & 15, fo = (l >> 4) * 8;
  f32x4 acc[4][4] = {};
  for (int kt = 0; kt < K; kt += 32) {
    #pragma unroll
    for (int u = 0; u < 2; ++u) {
      int c = tid + u * 256;
      int row = c >> 2, ko = (c & 3) << 3;
      uint4 av = *(const uint4*)(A + (size_t)(m0 + row) * K + kt + ko);
      *(uint4*)(&lsA[row][ko]) = av;
      int nr = n0 + row;
      uint4 bv = make_uint4(0u,0u,0u,0u);
      if (nr < N) bv = *(const uint4*)(W + (size_t)nr * K + kt + ko);
      *(uint4*)(&lsB[row][ko]) = bv;
    }
    __syncthreads();
    short8 af[4], bfv[4];
    #pragma unroll
    for (int i = 0; i < 4; ++i) af[i]  = *(const short8*)(&lsA[wm + i*16 + fr][fo]);
    #pragma unroll
    for (int j = 0; j < 4; ++j) bfv[j] = *(const short8*)(&lsB[wn + j*16 + fr][fo]);
    #pragma unroll
    for (int i = 0; i < 4; ++i)
      #pragma unroll
      for (int j = 0; j < 4; ++j)
        acc[i][j] = __builtin_amdgcn_mfma_f32_16x16x32_bf16(af[i], bfv[j], acc[i][j], 0, 0, 0);
    __syncthreads();
  }
  const int r0 = (l >> 4) * 4, cc = l & 15;
  #pragma unroll
  for (int j = 0; j < 4; ++j) {
    int col = n0 + wn + j*16 + cc;
    if (col >= N) continue;
    float bv = bias[col];
    #pragma unroll
    for (int i = 0; i < 4; ++i) {
      #pragma unroll
      for (int r = 0; r < 4; ++r) {
        int row = m0 + wm + i*16 + r0 + r;
        float v = acc[i][j][r] + bv;
        if (MODE == 1) {
          ((uint16_t*)out)[(size_t)row * N + col] = f2bf(v);
        } else if (MODE == 2) {
          int t = row & 63, n = row >> 6;
          if (t >= lens[n]) v = 0.f;
          ((float*)out)[(size_t)row * N + col] = v;
        } else {
          ((float*)out)[(size_t)row * N + col] = v;
        }
      }
    }
  }
}

// ---------------- MFMA-batched LSTM recurrence ----------------
// Block = 16 samples, 8 waves (512 thr). Wave w owns rows [w*16,w*16+16) of each
// of the 4 gate blocks of Whh, held as A-fragments in VGPRs (loaded once).
// Per t: B-frags from LDS h-tile (double-buffered), 16 MFMAs, += prefetched X,
// gate math in-lane (i/f/g/o same lane), 1 barrier.
__global__ __launch_bounds__(512) void k_lstm_mfma(
    const uint16_t* __restrict__ X,      // [NS*TT][512] bf16 = x@Wih^T + b
    const uint16_t* __restrict__ Whh,    // [512][128] bf16
    const float* __restrict__ h0i, const float* __restrict__ c0i,  // [NS][128] or null
    uint16_t* __restrict__ hout,         // [NS*TT][128] bf16
    float* __restrict__ hfin, float* __restrict__ cfin)            // [NS][128] or null
{
  __shared__ __align__(16) uint16_t hbuf[2][16][136];  // [buf][sample][h], pad->uniform banks
  const int n0 = blockIdx.x * 16;
  const int w = threadIdx.x >> 6, l = threadIdx.x & 63;
  const int s = l & 15;            // A-row within tile == B/C col (sample)
  const int hi4 = l >> 4;          // 0..3
  const int j0 = w*16 + hi4*4;     // this lane's hidden rows j0..j0+3

  // A-fragments: Whh rows, [gate][kstep]
  short8 afr[4][4];
  #pragma unroll
  for (int g = 0; g < 4; ++g)
    #pragma unroll
    for (int kk = 0; kk < 4; ++kk)
      afr[g][kk] = *(const short8*)(Whh + (size_t)(g*128 + w*16 + s)*128 + kk*32 + hi4*8);

  // state init
  f32x4 cst = {0.f, 0.f, 0.f, 0.f};
  if (c0i) cst = *(const f32x4*)(c0i + (size_t)(n0+s)*128 + j0);
  {
    uint16_t hb[4] = {0,0,0,0};
    if (h0i) {
      float4 hv = *(const float4*)(h0i + (size_t)(n0+s)*128 + j0);
      hb[0]=f2bf(hv.x); hb[1]=f2bf(hv.y); hb[2]=f2bf(hv.z); hb[3]=f2bf(hv.w);
    }
    *(uint2*)(&hbuf[0][s][j0]) = *(const uint2*)hb;
  }
  __syncthreads();

  const uint16_t* Xp = X + (size_t)(n0+s)*TT*512 + j0;
  uint2 xv[4], xvn[4];
  #pragma unroll
  for (int g = 0; g < 4; ++g) xv[g] = *(const uint2*)(Xp + g*128);

  float hfv[4] = {0.f,0.f,0.f,0.f};
  for (int t = 0; t < TT; ++t) {
    const int rb = t & 1;
    if (t + 1 < TT) {                      // prefetch next timestep's X
      const uint16_t* Xn = Xp + (size_t)(t+1)*512;
      #pragma unroll
      for (int g = 0; g < 4; ++g) xvn[g] = *(const uint2*)(Xn + g*128);
    }
    short8 bfr[4];
    #pragma unroll
    for (int kk = 0; kk < 4; ++kk)
      bfr[kk] = *(const short8*)(&hbuf[rb][s][kk*32 + hi4*8]);
    f32x4 acc[4] = {{0.f,0.f,0.f,0.f},{0.f,0.f,0.f,0.f},{0.f,0.f,0.f,0.f},{0.f,0.f,0.f,0.f}};
    #pragma unroll
    for (int kk = 0; kk < 4; ++kk)
      #pragma unroll
      for (int g = 0; g < 4; ++g)
        acc[g] = __builtin_amdgcn_mfma_f32_16x16x32_bf16(afr[g][kk], bfr[kk], acc[g], 0, 0, 0);
    uint16_t hb[4];
    #pragma unroll
    for (int r = 0; r < 4; ++r) {
      uint32_t wi = (r & 2) ? xv[0].y : xv[0].x;
      uint32_t wf = (r & 2) ? xv[1].y : xv[1].x;
      uint32_t wg = (r & 2) ? xv[2].y : xv[2].x;
      uint32_t wo = (r & 2) ? xv[3].y : xv[3].x;
      float zi = acc[0][r] + ((r & 1) ? bhi(wi) : blo(wi));
      float zf = acc[1][r] + ((r & 1) ? bhi(wf) : blo(wf));
      float zg = acc[2][r] + ((r & 1) ? bhi(wg) : blo(wg));
      float zo = acc[3][r] + ((r & 1) ? bhi(wo) : blo(wo));
      float cn = sigf(zf) * cst[r] + sigf(zi) * ftanh(zg);
      float h  = sigf(zo) * ftanh(cn);
      cst[r] = cn;
      hfv[r] = h;
      hb[r] = f2bf(h);
    }
    *(uint2*)(&hbuf[rb ^ 1][s][j0]) = *(const uint2*)hb;
    *(uint2*)(hout + ((size_t)(n0+s)*TT + t)*HD + j0) = *(const uint2*)hb;
    if (t + 1 < TT) {
      #pragma unroll
      for (int g = 0; g < 4; ++g) xv[g] = xvn[g];
    }
    __syncthreads();
  }
  if (hfin) *(float4*)(hfin + (size_t)(n0+s)*128 + j0) = make_float4(hfv[0],hfv[1],hfv[2],hfv[3]);
  if (cfin) *(float4*)(cfin + (size_t)(n0+s)*128 + j0) = make_float4(cst[0],cst[1],cst[2],cst[3]);
}

// ---------------- attention: per question n, keys staged in LDS ----------------
__global__ __launch_bounds__(256) void k_attn(
    const float* __restrict__ keys,     // [MT][128] f32
    const uint16_t* __restrict__ h1,    // [MT][128] bf16 (decoder layer-1 h)
    uint16_t* __restrict__ feat)        // [MT][896], writes cols 128..255 (ctx)
{
  __shared__ float ks[64][129];
  __shared__ float ps[4][64];
  const int n = blockIdx.x;
  for (int i = threadIdx.x; i < 64*128; i += 256)
    ks[i >> 7][i & 127] = keys[(size_t)n*8192 + i];
  __syncthreads();
  const int w = threadIdx.x >> 6, l = threadIdx.x & 63;
  for (int tt = 0; tt < 16; ++tt) {
    const int t = tt*4 + w;
    const int m = n*64 + t;
    const uint4* hp = (const uint4*)(h1 + (size_t)m*128);
    float s = 0.f;
    #pragma unroll
    for (int k = 0; k < 16; ++k) {
      uint4 hv = hp[k];
      s += ks[l][8*k+0]*blo(hv.x) + ks[l][8*k+1]*bhi(hv.x)
         + ks[l][8*k+2]*blo(hv.y) + ks[l][8*k+3]*bhi(hv.y)
         + ks[l][8*k+4]*blo(hv.z) + ks[l][8*k+5]*bhi(hv.z)
         + ks[l][8*k+6]*blo(hv.w) + ks[l][8*k+7]*bhi(hv.w);
    }
    float mx = s;
    #pragma unroll
    for (int o = 32; o; o >>= 1) mx = fmaxf(mx, __shfl_xor(mx, o));
    float p = __expf(s - mx);
    float sm = p;
    #pragma unroll
    for (int o = 32; o; o >>= 1) sm += __shfl_xor(sm, o);
    p /= sm;
    ps[w][l] = p;
    float c0 = 0.f, c1 = 0.f;
    #pragma unroll
    for (int q = 0; q < 64; ++q) {
      float pq = ps[w][q];
      c0 += pq * ks[q][l];
      c1 += pq * ks[q][l + 64];
    }
    feat[(size_t)m*896 + 128 + l] = f2bf(c0);
    feat[(size_t)m*896 + 192 + l] = f2bf(c1);
  }
}

// ---------------- feat assembly: cols 0..127 h1, 256..383 hist, 384..895 img ----------------
__global__ void k_feat(const uint16_t* __restrict__ h1, const float* __restrict__ img,
                       uint16_t* __restrict__ feat){
  int i = blockIdx.x * blockDim.x + threadIdx.x;    // one 8-elem chunk
  if (i >= MT*96) return;
  int m = i / 96, c8 = i - m*96;
  int c = c8 * 8;
  if (c < 128) {
    uint4 v = ((const uint4*)(h1 + (size_t)m*128))[c8];
    *(uint4*)(feat + (size_t)m*896 + c) = v;
  } else if (c < 256) {
    int n = m >> 6;
    uint4 v = make_uint4(0u,0u,0u,0u);
    if (n > 0) v = ((const uint4*)(h1 + ((size_t)(n-1)*64 + 63)*128))[c8 - 16];
    *(uint4*)(feat + (size_t)m*896 + 128 + c) = v;   // col = c+128 in [256,384)
  } else {
    const float4* ip = (const float4*)img;
    float4 f0 = ip[(c - 256) >> 2], f1 = ip[((c - 256) >> 2) + 1];
    uint16_t o[8];
    o[0]=f2bf(f0.x); o[1]=f2bf(f0.y); o[2]=f2bf(f0.z); o[3]=f2bf(f0.w);
    o[4]=f2bf(f1.x); o[5]=f2bf(f1.y); o[6]=f2bf(f1.z); o[7]=f2bf(f1.w);
    *(uint4*)(feat + (size_t)m*896 + 128 + c) = *(uint4*)o;  // col = c+128 in [384,896)
  }
}

extern "C" void kernel_launch(void* const* d_in, const int* in_sizes, int n_in,
                              void* d_out, int out_size, void* d_ws, size_t ws_size,
                              hipStream_t stream) {
  const int*   questions = (const int*)d_in[0];
  const int*   answers   = (const int*)d_in[1];
  const int*   lens      = (const int*)d_in[2];
  const float* img       = (const float*)d_in[3];
  const float* emb       = (const float*)d_in[4];
  const float* eWih0 = (const float*)d_in[5],  *eWhh0 = (const float*)d_in[6],  *eB0 = (const float*)d_in[7];
  const float* eWih1 = (const float*)d_in[8],  *eWhh1 = (const float*)d_in[9],  *eB1 = (const float*)d_in[10];
  const float* dWih0 = (const float*)d_in[11], *dWhh0 = (const float*)d_in[12], *dB0 = (const float*)d_in[13];
  const float* dWih1 = (const float*)d_in[14], *dWhh1 = (const float*)d_in[15], *dB1 = (const float*)d_in[16];
  const float* Wk   = (const float*)d_in[17], *bk   = (const float*)d_in[18];
  const float* Wout = (const float*)d_in[19], *bout = (const float*)d_in[20];

  char* ws = (char*)d_ws;
  size_t off = 0;
  auto alloc = [&](size_t n)->char* {
    char* p = ws + off; off += (n + 255) & ~(size_t)255; return p;
  };
  uint16_t* embP  = (uint16_t*)alloc((size_t)VD*128*2);
  uint16_t* wih0e = (uint16_t*)alloc(512*128*2);
  uint16_t* whh0e = (uint16_t*)alloc(512*128*2);
  uint16_t* wih1e = (uint16_t*)alloc(512*128*2);
  uint16_t* whh1e = (uint16_t*)alloc(512*128*2);
  uint16_t* wih0d = (uint16_t*)alloc(512*128*2);
  uint16_t* whh0d = (uint16_t*)alloc(512*128*2);
  uint16_t* wih1d = (uint16_t*)alloc(512*128*2);
  uint16_t* whh1d = (uint16_t*)alloc(512*128*2);
  uint16_t* wkb   = (uint16_t*)alloc(128*128*2);
  uint16_t* woutb = (uint16_t*)alloc((size_t)VD*896*2);
  uint16_t* embBuf= (uint16_t*)alloc((size_t)MT*128*2);
  uint16_t* Xbuf  = (uint16_t*)alloc((size_t)MT*512*2);
  uint16_t* hA    = (uint16_t*)alloc((size_t)MT*128*2);
  uint16_t* h1b   = (uint16_t*)alloc((size_t)MT*128*2);
  float*    keysf = (float*)   alloc((size_t)MT*128*4);
  uint16_t* feat  = (uint16_t*)alloc((size_t)MT*896*2);
  float* eh0 = (float*)alloc(NS*128*4);
  float* ec0 = (float*)alloc(NS*128*4);
  float* eh1 = (float*)alloc(NS*128*4);
  float* ec1 = (float*)alloc(NS*128*4);
  if (off > ws_size) return;  // workspace too small; fail visibly

  // 1) convert all weights/emb to bf16 (padded K where needed)
  ConvJobs jobs;
  jobs.j[0]  = {emb,   embP,  VD, ED, 128};
  jobs.j[1]  = {eWih0, wih0e, 512, ED, 128};
  jobs.j[2]  = {eWhh0, whh0e, 512, 128, 128};
  jobs.j[3]  = {eWih1, wih1e, 512, 128, 128};
  jobs.j[4]  = {eWhh1, whh1e, 512, 128, 128};
  jobs.j[5]  = {dWih0, wih0d, 512, ED, 128};
  jobs.j[6]  = {dWhh0, whh0d, 512, 128, 128};
  jobs.j[7]  = {dWih1, wih1d, 512, 128, 128};
  jobs.j[8]  = {dWhh1, whh1d, 512, 128, 128};
  jobs.j[9]  = {Wk,    wkb,   128, 128, 128};
  jobs.j[10] = {Wout,  woutb, VD, 896, 896};
  hipLaunchKernelGGL(k_convert, dim3(1024), dim3(256), 0, stream, jobs);

  // ---- encoder ----
  hipLaunchKernelGGL(k_gather, dim3(MT*16/256), dim3(256), 0, stream, embP, questions, embBuf);
  hipLaunchKernelGGL(k_gemm<1>, dim3(MT/128, 4), dim3(256), 0, stream, embBuf, wih0e, eB0, Xbuf, 512, 128, nullptr);
  hipLaunchKernelGGL(k_lstm_mfma, dim3(NS/16), dim3(512), 0, stream, Xbuf, whh0e, (const float*)nullptr, (const float*)nullptr, hA, eh0, ec0);
  hipLaunchKernelGGL(k_gemm<1>, dim3(MT/128, 4), dim3(256), 0, stream, hA, wih1e, eB1, Xbuf, 512, 128, nullptr);
  hipLaunchKernelGGL(k_lstm_mfma, dim3(NS/16), dim3(512), 0, stream, Xbuf, whh1e, (const float*)nullptr, (const float*)nullptr, h1b, eh1, ec1);
  hipLaunchKernelGGL(k_gemm<0>, dim3(MT/128, 1), dim3(256), 0, stream, h1b, wkb, bk, keysf, 128, 128, nullptr);

  // ---- decoder (parallel across questions; history only affects logits) ----
  hipLaunchKernelGGL(k_gather, dim3(MT*16/256), dim3(256), 0, stream, embP, answers, embBuf);
  hipLaunchKernelGGL(k_gemm<1>, dim3(MT/128, 4), dim3(256), 0, stream, embBuf, wih0d, dB0, Xbuf, 512, 128, nullptr);
  hipLaunchKernelGGL(k_lstm_mfma, dim3(NS/16), dim3(512), 0, stream, Xbuf, whh0d, eh0, ec0, hA, (float*)nullptr, (float*)nullptr);
  hipLaunchKernelGGL(k_gemm<1>, dim3(MT/128, 4), dim3(256), 0, stream, hA, wih1d, dB1, Xbuf, 512, 128, nullptr);
  hipLaunchKernelGGL(k_lstm_mfma, dim3(NS/16), dim3(512), 0, stream, Xbuf, whh1d, eh1, ec1, h1b, (float*)nullptr, (float*)nullptr);

  // ---- attention + feat assembly + output projection ----
  hipLaunchKernelGGL(k_attn, dim3(NS), dim3(256), 0, stream, keysf, h1b, feat);
  hipLaunchKernelGGL(k_feat, dim3((MT*96+255)/256), dim3(256), 0, stream, h1b, img, feat);
  hipLaunchKernelGGL(k_gemm<2>, dim3(MT/128, 8), dim3(256), 0, stream, feat, woutb, bout, d_out, VD, 896, lens);
}

// Round 4
// 901.455 us; speedup vs baseline: 1.4362x; 1.0336x over previous
//
#include <hip/hip_runtime.h>
#include <stdint.h>

#define HD   128
#define ED   100
#define VD   1000
#define FDV  512
#define NS   512
#define TT   64
#define MT   (NS*TT)   // 32768

typedef __attribute__((ext_vector_type(8))) short  short8;
typedef __attribute__((ext_vector_type(4))) float  f32x4;

typedef const __attribute__((address_space(1))) uint16_t* gas_u16;
typedef __attribute__((address_space(3))) uint16_t*       las_u16;

__device__ __forceinline__ float blo(uint32_t u){ return __uint_as_float(u << 16); }
__device__ __forceinline__ float bhi(uint32_t u){ return __uint_as_float(u & 0xffff0000u); }
__device__ __forceinline__ uint16_t f2bf(float f){
  uint32_t x = __float_as_uint(f);
  return (uint16_t)((x + 0x7fffu + ((x >> 16) & 1u)) >> 16);
}
__device__ __forceinline__ float sigf(float x){ return 1.f/(1.f+__expf(-x)); }
__device__ __forceinline__ float ftanh(float x){
  float ax = fabsf(x);
  float e = __expf(-2.f*ax);
  float t = (1.f - e) / (1.f + e);
  return copysignf(t, x);
}

// ---------------- weight/emb conversion (f32 -> bf16, padded) ----------------
// R = padded rows, R0 = valid rows (rest zero), C valid cols, Cp padded cols.
struct ConvJob { const float* s; uint16_t* d; int R, R0, C, Cp; };
struct ConvJobs { ConvJob j[12]; };

__global__ void k_convert(ConvJobs jobs){
  int stride = gridDim.x * blockDim.x;
  int tid0 = blockIdx.x * blockDim.x + threadIdx.x;
  for (int ji = 0; ji < 12; ++ji){
    const ConvJob jb = jobs.j[ji];
    int total = jb.R * jb.Cp;
    for (int i = tid0; i < total; i += stride){
      int r = i / jb.Cp, c = i - r*jb.Cp;
      float v = (r < jb.R0 && c < jb.C) ? jb.s[(size_t)r*jb.C + c] : 0.f;
      jb.d[i] = f2bf(v);
    }
  }
}

// ---------------- embedding gather: tok[m] -> bf16 padded rows [MT][128] ----------------
__global__ void k_gather(const uint16_t* __restrict__ embP, const int* __restrict__ tok,
                         uint16_t* __restrict__ out){
  int i = blockIdx.x * blockDim.x + threadIdx.x;   // one uint4 (8 bf16) per thread
  if (i >= MT*16) return;
  int m = i >> 4, c8 = i & 15;
  int v = tok[m];
  ((uint4*)(out + (size_t)m*128))[c8] = ((const uint4*)(embP + (size_t)v*128))[c8];
}

// ---------------- bf16 MFMA GEMM (m97-style): global_load_lds staging ----------------
// C[M,N] = A[M,K] @ W[Nb,K]^T + bias, 128x128 tile, BK=32, linear LDS.
// W must have >= ceil(N/128)*128 valid (zero-padded) rows.
// MODE 0: f32 out; 1: bf16 out; 2: f32 out with t>=lens[n] row masking
template<int MODE>
__global__ __launch_bounds__(256) void k_gemm(
    const uint16_t* __restrict__ A, const uint16_t* __restrict__ W,
    const float* __restrict__ bias, void* __restrict__ out,
    int N, int K, const int* __restrict__ lens)
{
  __shared__ __align__(16) uint16_t lsA[128][32];
  __shared__ __align__(16) uint16_t lsB[128][32];
  const int tid = threadIdx.x;
  const int n0 = blockIdx.x * 128, m0 = blockIdx.y * 128;
  const int l = tid & 63, w = tid >> 6;
  const int wm = (w >> 1) * 64, wn = (w & 1) * 64;
  const int fr = l & 15, fo = (l >> 4) * 8;
  // staging coords: lane l of wave w, round u covers LDS linear bytes
  // w*1024 + u*4096 + l*16  ->  row = u*64 + w*16 + (l>>2), col elem = (l&3)*8
  const int srow = w*16 + (l >> 2);
  const int sce  = (l & 3) * 8;
  f32x4 acc[4][4] = {};
  for (int kt = 0; kt < K; kt += 32) {
    #pragma unroll
    for (int u = 0; u < 2; ++u) {
      const int row = u*64 + srow;
      const int lo  = w*512 + u*2048;          // LDS elem offset (wave-uniform)
      __builtin_amdgcn_global_load_lds(
          (gas_u16)(A + (size_t)(m0 + row) * K + kt + sce),
          (las_u16)(&lsA[0][0] + lo), 16, 0, 0);
      __builtin_amdgcn_global_load_lds(
          (gas_u16)(W + (size_t)(n0 + row) * K + kt + sce),
          (las_u16)(&lsB[0][0] + lo), 16, 0, 0);
    }
    __syncthreads();
    short8 af[4], bfv[4];
    #pragma unroll
    for (int i = 0; i < 4; ++i) af[i]  = *(const short8*)(&lsA[wm + i*16 + fr][fo]);
    #pragma unroll
    for (int j = 0; j < 4; ++j) bfv[j] = *(const short8*)(&lsB[wn + j*16 + fr][fo]);
    #pragma unroll
    for (int i = 0; i < 4; ++i)
      #pragma unroll
      for (int j = 0; j < 4; ++j)
        acc[i][j] = __builtin_amdgcn_mfma_f32_16x16x32_bf16(af[i], bfv[j], acc[i][j], 0, 0, 0);
    __syncthreads();
  }
  const int r0 = (l >> 4) * 4, cc = l & 15;
  #pragma unroll
  for (int j = 0; j < 4; ++j) {
    int col = n0 + wn + j*16 + cc;
    if (col >= N) continue;
    float bv = bias[col];
    #pragma unroll
    for (int i = 0; i < 4; ++i) {
      #pragma unroll
      for (int r = 0; r < 4; ++r) {
        int row = m0 + wm + i*16 + r0 + r;
        float v = acc[i][j][r] + bv;
        if (MODE == 1) {
          ((uint16_t*)out)[(size_t)row * N + col] = f2bf(v);
        } else if (MODE == 2) {
          int t = row & 63, n = row >> 6;
          if (t >= lens[n]) v = 0.f;
          ((float*)out)[(size_t)row * N + col] = v;
        } else {
          ((float*)out)[(size_t)row * N + col] = v;
        }
      }
    }
  }
}

// ---------------- MFMA-batched LSTM recurrence ----------------
__global__ __launch_bounds__(512) void k_lstm_mfma(
    const uint16_t* __restrict__ X,      // [NS*TT][512] bf16 = x@Wih^T + b
    const uint16_t* __restrict__ Whh,    // [512][128] bf16
    const float* __restrict__ h0i, const float* __restrict__ c0i,  // [NS][128] or null
    uint16_t* __restrict__ hout,         // [NS*TT][128] bf16
    float* __restrict__ hfin, float* __restrict__ cfin)            // [NS][128] or null
{
  __shared__ __align__(16) uint16_t hbuf[2][16][136];
  const int n0 = blockIdx.x * 16;
  const int w = threadIdx.x >> 6, l = threadIdx.x & 63;
  const int s = l & 15;
  const int hi4 = l >> 4;
  const int j0 = w*16 + hi4*4;

  short8 afr[4][4];
  #pragma unroll
  for (int g = 0; g < 4; ++g)
    #pragma unroll
    for (int kk = 0; kk < 4; ++kk)
      afr[g][kk] = *(const short8*)(Whh + (size_t)(g*128 + w*16 + s)*128 + kk*32 + hi4*8);

  f32x4 cst = {0.f, 0.f, 0.f, 0.f};
  if (c0i) cst = *(const f32x4*)(c0i + (size_t)(n0+s)*128 + j0);
  {
    uint16_t hb[4] = {0,0,0,0};
    if (h0i) {
      float4 hv = *(const float4*)(h0i + (size_t)(n0+s)*128 + j0);
      hb[0]=f2bf(hv.x); hb[1]=f2bf(hv.y); hb[2]=f2bf(hv.z); hb[3]=f2bf(hv.w);
    }
    *(uint2*)(&hbuf[0][s][j0]) = *(const uint2*)hb;
  }
  __syncthreads();

  const uint16_t* Xp = X + (size_t)(n0+s)*TT*512 + j0;
  uint2 xv[4], xvn[4];
  #pragma unroll
  for (int g = 0; g < 4; ++g) xv[g] = *(const uint2*)(Xp + g*128);

  float hfv[4] = {0.f,0.f,0.f,0.f};
  for (int t = 0; t < TT; ++t) {
    const int rb = t & 1;
    if (t + 1 < TT) {
      const uint16_t* Xn = Xp + (size_t)(t+1)*512;
      #pragma unroll
      for (int g = 0; g < 4; ++g) xvn[g] = *(const uint2*)(Xn + g*128);
    }
    short8 bfr[4];
    #pragma unroll
    for (int kk = 0; kk < 4; ++kk)
      bfr[kk] = *(const short8*)(&hbuf[rb][s][kk*32 + hi4*8]);
    f32x4 acc[4] = {{0.f,0.f,0.f,0.f},{0.f,0.f,0.f,0.f},{0.f,0.f,0.f,0.f},{0.f,0.f,0.f,0.f}};
    #pragma unroll
    for (int kk = 0; kk < 4; ++kk)
      #pragma unroll
      for (int g = 0; g < 4; ++g)
        acc[g] = __builtin_amdgcn_mfma_f32_16x16x32_bf16(afr[g][kk], bfr[kk], acc[g], 0, 0, 0);
    uint16_t hb[4];
    #pragma unroll
    for (int r = 0; r < 4; ++r) {
      uint32_t wi = (r & 2) ? xv[0].y : xv[0].x;
      uint32_t wf = (r & 2) ? xv[1].y : xv[1].x;
      uint32_t wg = (r & 2) ? xv[2].y : xv[2].x;
      uint32_t wo = (r & 2) ? xv[3].y : xv[3].x;
      float zi = acc[0][r] + ((r & 1) ? bhi(wi) : blo(wi));
      float zf = acc[1][r] + ((r & 1) ? bhi(wf) : blo(wf));
      float zg = acc[2][r] + ((r & 1) ? bhi(wg) : blo(wg));
      float zo = acc[3][r] + ((r & 1) ? bhi(wo) : blo(wo));
      float cn = sigf(zf) * cst[r] + sigf(zi) * ftanh(zg);
      float h  = sigf(zo) * ftanh(cn);
      cst[r] = cn;
      hfv[r] = h;
      hb[r] = f2bf(h);
    }
    *(uint2*)(&hbuf[rb ^ 1][s][j0]) = *(const uint2*)hb;
    *(uint2*)(hout + ((size_t)(n0+s)*TT + t)*HD + j0) = *(const uint2*)hb;
    if (t + 1 < TT) {
      #pragma unroll
      for (int g = 0; g < 4; ++g) xv[g] = xvn[g];
    }
    __syncthreads();
  }
  if (hfin) *(float4*)(hfin + (size_t)(n0+s)*128 + j0) = make_float4(hfv[0],hfv[1],hfv[2],hfv[3]);
  if (cfin) *(float4*)(cfin + (size_t)(n0+s)*128 + j0) = make_float4(cst[0],cst[1],cst[2],cst[3]);
}

// ---------------- fused attention + feat assembly ----------------
// Per question n: ctx = softmax(keys @ h1_t) @ keys; write full feat row:
// [0:128)=h1_t, [128:256)=ctx, [256:384)=hist, [384:896)=img (bf16).
__global__ __launch_bounds__(256) void k_attn(
    const float* __restrict__ keys,     // [MT][128] f32
    const uint16_t* __restrict__ h1,    // [MT][128] bf16
    const uint16_t* __restrict__ imgb,  // [512] bf16
    uint16_t* __restrict__ feat)        // [MT][896]
{
  __shared__ float ks[64][129];
  __shared__ float ps[4][64];
  const int n = blockIdx.x;
  for (int i = threadIdx.x; i < 64*128; i += 256)
    ks[i >> 7][i & 127] = keys[(size_t)n*8192 + i];
  const int w = threadIdx.x >> 6, l = threadIdx.x & 63;
  uint32_t hd = 0;
  if (n > 0) hd = ((const uint32_t*)(h1 + ((size_t)(n-1)*64 + 63)*128))[l];
  const uint4 iv = ((const uint4*)imgb)[l];
  __syncthreads();
  for (int tt = 0; tt < 16; ++tt) {
    const int t = tt*4 + w;
    const size_t m = (size_t)n*64 + t;
    const uint4* hp = (const uint4*)(h1 + m*128);
    float s = 0.f;
    #pragma unroll
    for (int k = 0; k < 16; ++k) {
      uint4 hv = hp[k];
      s += ks[l][8*k+0]*blo(hv.x) + ks[l][8*k+1]*bhi(hv.x)
         + ks[l][8*k+2]*blo(hv.y) + ks[l][8*k+3]*bhi(hv.y)
         + ks[l][8*k+4]*blo(hv.z) + ks[l][8*k+5]*bhi(hv.z)
         + ks[l][8*k+6]*blo(hv.w) + ks[l][8*k+7]*bhi(hv.w);
    }
    float mx = s;
    #pragma unroll
    for (int o = 32; o; o >>= 1) mx = fmaxf(mx, __shfl_xor(mx, o));
    float p = __expf(s - mx);
    float sm = p;
    #pragma unroll
    for (int o = 32; o; o >>= 1) sm += __shfl_xor(sm, o);
    p /= sm;
    ps[w][l] = p;
    float c0 = 0.f, c1 = 0.f;
    #pragma unroll
    for (int q = 0; q < 64; ++q) {
      float pq = ps[w][q];
      c0 += pq * ks[q][l];
      c1 += pq * ks[q][l + 64];
    }
    uint16_t* fr_ = feat + m*896;
    ((uint32_t*)fr_)[l] = ((const uint32_t*)(h1 + m*128))[l];  // h1 copy
    fr_[128 + l] = f2bf(c0);
    fr_[192 + l] = f2bf(c1);
    ((uint32_t*)(fr_ + 256))[l] = hd;                          // history
    ((uint4*)(fr_ + 384))[l] = iv;                             // img
  }
}

extern "C" void kernel_launch(void* const* d_in, const int* in_sizes, int n_in,
                              void* d_out, int out_size, void* d_ws, size_t ws_size,
                              hipStream_t stream) {
  const int*   questions = (const int*)d_in[0];
  const int*   answers   = (const int*)d_in[1];
  const int*   lens      = (const int*)d_in[2];
  const float* img       = (const float*)d_in[3];
  const float* emb       = (const float*)d_in[4];
  const float* eWih0 = (const float*)d_in[5],  *eWhh0 = (const float*)d_in[6],  *eB0 = (const float*)d_in[7];
  const float* eWih1 = (const float*)d_in[8],  *eWhh1 = (const float*)d_in[9],  *eB1 = (const float*)d_in[10];
  const float* dWih0 = (const float*)d_in[11], *dWhh0 = (const float*)d_in[12], *dB0 = (const float*)d_in[13];
  const float* dWih1 = (const float*)d_in[14], *dWhh1 = (const float*)d_in[15], *dB1 = (const float*)d_in[16];
  const float* Wk   = (const float*)d_in[17], *bk   = (const float*)d_in[18];
  const float* Wout = (const float*)d_in[19], *bout = (const float*)d_in[20];

  char* ws = (char*)d_ws;
  size_t off = 0;
  auto alloc = [&](size_t n)->char* {
    char* p = ws + off; off += (n + 255) & ~(size_t)255; return p;
  };
  uint16_t* embP  = (uint16_t*)alloc((size_t)VD*128*2);
  uint16_t* wih0e = (uint16_t*)alloc(512*128*2);
  uint16_t* whh0e = (uint16_t*)alloc(512*128*2);
  uint16_t* wih1e = (uint16_t*)alloc(512*128*2);
  uint16_t* whh1e = (uint16_t*)alloc(512*128*2);
  uint16_t* wih0d = (uint16_t*)alloc(512*128*2);
  uint16_t* whh0d = (uint16_t*)alloc(512*128*2);
  uint16_t* wih1d = (uint16_t*)alloc(512*128*2);
  uint16_t* whh1d = (uint16_t*)alloc(512*128*2);
  uint16_t* wkb   = (uint16_t*)alloc(128*128*2);
  uint16_t* woutb = (uint16_t*)alloc((size_t)1024*896*2);   // padded to 1024 rows
  uint16_t* imgb  = (uint16_t*)alloc(512*2);
  uint16_t* embBuf= (uint16_t*)alloc((size_t)MT*128*2);
  uint16_t* Xbuf  = (uint16_t*)alloc((size_t)MT*512*2);
  uint16_t* hA    = (uint16_t*)alloc((size_t)MT*128*2);
  uint16_t* h1b   = (uint16_t*)alloc((size_t)MT*128*2);
  float*    keysf = (float*)   alloc((size_t)MT*128*4);
  uint16_t* feat  = (uint16_t*)alloc((size_t)MT*896*2);
  float* eh0 = (float*)alloc(NS*128*4);
  float* ec0 = (float*)alloc(NS*128*4);
  float* eh1 = (float*)alloc(NS*128*4);
  float* ec1 = (float*)alloc(NS*128*4);
  if (off > ws_size) return;  // workspace too small; fail visibly

  ConvJobs jobs;
  jobs.j[0]  = {emb,   embP,  VD,  VD,  ED,  128};
  jobs.j[1]  = {eWih0, wih0e, 512, 512, ED,  128};
  jobs.j[2]  = {eWhh0, whh0e, 512, 512, 128, 128};
  jobs.j[3]  = {eWih1, wih1e, 512, 512, 128, 128};
  jobs.j[4]  = {eWhh1, whh1e, 512, 512, 128, 128};
  jobs.j[5]  = {dWih0, wih0d, 512, 512, ED,  128};
  jobs.j[6]  = {dWhh0, whh0d, 512, 512, 128, 128};
  jobs.j[7]  = {dWih1, wih1d, 512, 512, 128, 128};
  jobs.j[8]  = {dWhh1, whh1d, 512, 512, 128, 128};
  jobs.j[9]  = {Wk,    wkb,   128, 128, 128, 128};
  jobs.j[10] = {Wout,  woutb, 1024, VD, 896, 896};
  jobs.j[11] = {img,   imgb,  1,   1,   512, 512};
  hipLaunchKernelGGL(k_convert, dim3(1024), dim3(256), 0, stream, jobs);

  // ---- encoder ----
  hipLaunchKernelGGL(k_gather, dim3(MT*16/256), dim3(256), 0, stream, embP, questions, embBuf);
  hipLaunchKernelGGL(k_gemm<1>, dim3(4, MT/128), dim3(256), 0, stream, embBuf, wih0e, eB0, Xbuf, 512, 128, nullptr);
  hipLaunchKernelGGL(k_lstm_mfma, dim3(NS/16), dim3(512), 0, stream, Xbuf, whh0e, (const float*)nullptr, (const float*)nullptr, hA, eh0, ec0);
  hipLaunchKernelGGL(k_gemm<1>, dim3(4, MT/128), dim3(256), 0, stream, hA, wih1e, eB1, Xbuf, 512, 128, nullptr);
  hipLaunchKernelGGL(k_lstm_mfma, dim3(NS/16), dim3(512), 0, stream, Xbuf, whh1e, (const float*)nullptr, (const float*)nullptr, h1b, eh1, ec1);
  hipLaunchKernelGGL(k_gemm<0>, dim3(1, MT/128), dim3(256), 0, stream, h1b, wkb, bk, keysf, 128, 128, nullptr);

  // ---- decoder ----
  hipLaunchKernelGGL(k_gather, dim3(MT*16/256), dim3(256), 0, stream, embP, answers, embBuf);
  hipLaunchKernelGGL(k_gemm<1>, dim3(4, MT/128), dim3(256), 0, stream, embBuf, wih0d, dB0, Xbuf, 512, 128, nullptr);
  hipLaunchKernelGGL(k_lstm_mfma, dim3(NS/16), dim3(512), 0, stream, Xbuf, whh0d, eh0, ec0, hA, (float*)nullptr, (float*)nullptr);
  hipLaunchKernelGGL(k_gemm<1>, dim3(4, MT/128), dim3(256), 0, stream, hA, wih1d, dB1, Xbuf, 512, 128, nullptr);
  hipLaunchKernelGGL(k_lstm_mfma, dim3(NS/16), dim3(512), 0, stream, Xbuf, whh1d, eh1, ec1, h1b, (float*)nullptr, (float*)nullptr);

  // ---- fused attention/feat + output projection ----
  hipLaunchKernelGGL(k_attn, dim3(NS), dim3(256), 0, stream, keysf, h1b, imgb, feat);
  hipLaunchKernelGGL(k_gemm<2>, dim3(8, MT/128), dim3(256), 0, stream, feat, woutb, bout, d_out, VD, 896, lens);
}

// Round 5
// 890.732 us; speedup vs baseline: 1.4535x; 1.0120x over previous
//
#include <hip/hip_runtime.h>
#include <stdint.h>

#define HD   128
#define ED   100
#define VD   1000
#define FDV  512
#define NS   512
#define TT   64
#define MT   (NS*TT)   // 32768

typedef __attribute__((ext_vector_type(8))) short  short8;
typedef __attribute__((ext_vector_type(4))) float  f32x4;

typedef const __attribute__((address_space(1))) uint16_t* gas_u16;
typedef __attribute__((address_space(3))) uint16_t*       las_u16;

__device__ __forceinline__ float blo(uint32_t u){ return __uint_as_float(u << 16); }
__device__ __forceinline__ float bhi(uint32_t u){ return __uint_as_float(u & 0xffff0000u); }
__device__ __forceinline__ uint16_t f2bf(float f){
  uint32_t x = __float_as_uint(f);
  return (uint16_t)((x + 0x7fffu + ((x >> 16) & 1u)) >> 16);
}
__device__ __forceinline__ float sigf(float x){ return 1.f/(1.f+__expf(-x)); }
__device__ __forceinline__ float ftanh(float x){
  float ax = fabsf(x);
  float e = __expf(-2.f*ax);
  float t = (1.f - e) / (1.f + e);
  return copysignf(t, x);
}
// LDS-only barrier: do NOT drain vmcnt (keeps prefetch loads / stores in flight).
__device__ __forceinline__ void lds_barrier(){
  asm volatile("s_waitcnt lgkmcnt(0)" ::: "memory");
  __builtin_amdgcn_s_barrier();
}

// ---------------- weight/emb conversion (f32 -> bf16, padded) ----------------
struct ConvJob { const float* s; uint16_t* d; int R, R0, C, Cp; };
struct ConvJobs { ConvJob j[12]; };

__global__ void k_convert(ConvJobs jobs){
  int stride = gridDim.x * blockDim.x;
  int tid0 = blockIdx.x * blockDim.x + threadIdx.x;
  for (int ji = 0; ji < 12; ++ji){
    const ConvJob jb = jobs.j[ji];
    int total = jb.R * jb.Cp;
    for (int i = tid0; i < total; i += stride){
      int r = i / jb.Cp, c = i - r*jb.Cp;
      float v = (r < jb.R0 && c < jb.C) ? jb.s[(size_t)r*jb.C + c] : 0.f;
      jb.d[i] = f2bf(v);
    }
  }
}

// ---------------- bf16 MFMA GEMM: global_load_lds staging, optional row-gather ----
// C[M,N] = A[M,K] @ W[Nb,K]^T + bias, 128x128 tile, BK=32, linear LDS.
// tok != null: A-row m is gathered from A[tok[m]] (embedding lookup fused).
// MODE 0: f32 out; 2: f32 out with t>=lens[n] row masking;
// MODE 3: bf16 out remapped to LSTM block layout [n/16][t][16][512] (N must be 512).
template<int MODE>
__global__ __launch_bounds__(256) void k_gemm(
    const uint16_t* __restrict__ A, const uint16_t* __restrict__ W,
    const float* __restrict__ bias, void* __restrict__ out,
    int N, int K, const int* __restrict__ lens, const int* __restrict__ tok)
{
  __shared__ __align__(16) uint16_t lsA[128][32];
  __shared__ __align__(16) uint16_t lsB[128][32];
  const int tid = threadIdx.x;
  const int n0 = blockIdx.x * 128, m0 = blockIdx.y * 128;
  const int l = tid & 63, w = tid >> 6;
  const int wm = (w >> 1) * 64, wn = (w & 1) * 64;
  const int fr = l & 15, fo = (l >> 4) * 8;
  // staging coords: lane l of wave w, round u: row = u*64 + w*16 + (l>>2), col = (l&3)*8
  const int srow = w*16 + (l >> 2);
  const int sce  = (l & 3) * 8;
  const int ar0 = m0 + srow, ar1 = m0 + 64 + srow;
  const size_t ab0 = (tok ? (size_t)tok[ar0] : (size_t)ar0) * K;
  const size_t ab1 = (tok ? (size_t)tok[ar1] : (size_t)ar1) * K;
  f32x4 acc[4][4] = {};
  for (int kt = 0; kt < K; kt += 32) {
    {
      __builtin_amdgcn_global_load_lds(
          (gas_u16)(A + ab0 + kt + sce),
          (las_u16)(&lsA[0][0] + w*512), 16, 0, 0);
      __builtin_amdgcn_global_load_lds(
          (gas_u16)(W + (size_t)(n0 + srow) * K + kt + sce),
          (las_u16)(&lsB[0][0] + w*512), 16, 0, 0);
      __builtin_amdgcn_global_load_lds(
          (gas_u16)(A + ab1 + kt + sce),
          (las_u16)(&lsA[0][0] + w*512 + 2048), 16, 0, 0);
      __builtin_amdgcn_global_load_lds(
          (gas_u16)(W + (size_t)(n0 + 64 + srow) * K + kt + sce),
          (las_u16)(&lsB[0][0] + w*512 + 2048), 16, 0, 0);
    }
    __syncthreads();
    short8 af[4], bfv[4];
    #pragma unroll
    for (int i = 0; i < 4; ++i) af[i]  = *(const short8*)(&lsA[wm + i*16 + fr][fo]);
    #pragma unroll
    for (int j = 0; j < 4; ++j) bfv[j] = *(const short8*)(&lsB[wn + j*16 + fr][fo]);
    #pragma unroll
    for (int i = 0; i < 4; ++i)
      #pragma unroll
      for (int j = 0; j < 4; ++j)
        acc[i][j] = __builtin_amdgcn_mfma_f32_16x16x32_bf16(af[i], bfv[j], acc[i][j], 0, 0, 0);
    __syncthreads();
  }
  const int r0 = (l >> 4) * 4, cc = l & 15;
  #pragma unroll
  for (int j = 0; j < 4; ++j) {
    int col = n0 + wn + j*16 + cc;
    if (col >= N) continue;
    float bv = bias[col];
    #pragma unroll
    for (int i = 0; i < 4; ++i) {
      #pragma unroll
      for (int r = 0; r < 4; ++r) {
        int row = m0 + wm + i*16 + r0 + r;
        float v = acc[i][j][r] + bv;
        if (MODE == 3) {
          int t = row & 63, n = row >> 6;
          size_t prow = ((size_t)(n >> 4)*64 + (size_t)t)*16 + (n & 15);
          ((uint16_t*)out)[prow * 512 + col] = f2bf(v);
        } else if (MODE == 2) {
          int t = row & 63, n = row >> 6;
          if (t >= lens[n]) v = 0.f;
          ((float*)out)[(size_t)row * N + col] = v;
        } else {
          ((float*)out)[(size_t)row * N + col] = v;
        }
      }
    }
  }
}

// ---------------- MFMA-batched LSTM recurrence ----------------
// Block = 16 samples, 8 waves. X in block layout [b][t][16][512].
// Per t: ds_read h-frags, 16 MFMA, gates in-lane, ds_write; lgkm-only barrier
// keeps X prefetch loads and hout stores in flight across steps.
__global__ __launch_bounds__(512) void k_lstm_mfma(
    const uint16_t* __restrict__ X,      // [NS/16][TT][16][512] bf16 = x@Wih^T + b
    const uint16_t* __restrict__ Whh,    // [512][128] bf16
    const float* __restrict__ h0i, const float* __restrict__ c0i,  // [NS][128] or null
    uint16_t* __restrict__ hout,         // [MT][128] bf16 (m = n*TT + t)
    float* __restrict__ hfin, float* __restrict__ cfin)            // [NS][128] or null
{
  __shared__ __align__(16) uint16_t hbuf[2][16][136];
  const int n0 = blockIdx.x * 16;
  const int w = threadIdx.x >> 6, l = threadIdx.x & 63;
  const int s = l & 15;
  const int hi4 = l >> 4;
  const int j0 = w*16 + hi4*4;

  short8 afr[4][4];
  #pragma unroll
  for (int g = 0; g < 4; ++g)
    #pragma unroll
    for (int kk = 0; kk < 4; ++kk)
      afr[g][kk] = *(const short8*)(Whh + (size_t)(g*128 + w*16 + s)*128 + kk*32 + hi4*8);

  f32x4 cst = {0.f, 0.f, 0.f, 0.f};
  if (c0i) cst = *(const f32x4*)(c0i + (size_t)(n0+s)*128 + j0);
  {
    uint16_t hb[4] = {0,0,0,0};
    if (h0i) {
      float4 hv = *(const float4*)(h0i + (size_t)(n0+s)*128 + j0);
      hb[0]=f2bf(hv.x); hb[1]=f2bf(hv.y); hb[2]=f2bf(hv.z); hb[3]=f2bf(hv.w);
    }
    *(uint2*)(&hbuf[0][s][j0]) = *(const uint2*)hb;
  }
  __syncthreads();

  // block-contiguous X: per step one 16KB chunk
  const uint16_t* Xp = X + (size_t)blockIdx.x * TT * 8192 + s*512 + j0;
  uint2 xv[4], xvn[4];
  #pragma unroll
  for (int g = 0; g < 4; ++g) xv[g] = *(const uint2*)(Xp + g*128);

  float hfv[4] = {0.f,0.f,0.f,0.f};
  for (int t = 0; t < TT; ++t) {
    const int rb = t & 1;
    if (t + 1 < TT) {
      const uint16_t* Xn = Xp + (size_t)(t+1)*8192;
      #pragma unroll
      for (int g = 0; g < 4; ++g) xvn[g] = *(const uint2*)(Xn + g*128);
    }
    short8 bfr[4];
    #pragma unroll
    for (int kk = 0; kk < 4; ++kk)
      bfr[kk] = *(const short8*)(&hbuf[rb][s][kk*32 + hi4*8]);
    f32x4 acc[4] = {{0.f,0.f,0.f,0.f},{0.f,0.f,0.f,0.f},{0.f,0.f,0.f,0.f},{0.f,0.f,0.f,0.f}};
    #pragma unroll
    for (int kk = 0; kk < 4; ++kk)
      #pragma unroll
      for (int g = 0; g < 4; ++g)
        acc[g] = __builtin_amdgcn_mfma_f32_16x16x32_bf16(afr[g][kk], bfr[kk], acc[g], 0, 0, 0);
    uint16_t hb[4];
    #pragma unroll
    for (int r = 0; r < 4; ++r) {
      uint32_t wi = (r & 2) ? xv[0].y : xv[0].x;
      uint32_t wf = (r & 2) ? xv[1].y : xv[1].x;
      uint32_t wg = (r & 2) ? xv[2].y : xv[2].x;
      uint32_t wo = (r & 2) ? xv[3].y : xv[3].x;
      float zi = acc[0][r] + ((r & 1) ? bhi(wi) : blo(wi));
      float zf = acc[1][r] + ((r & 1) ? bhi(wf) : blo(wf));
      float zg = acc[2][r] + ((r & 1) ? bhi(wg) : blo(wg));
      float zo = acc[3][r] + ((r & 1) ? bhi(wo) : blo(wo));
      float cn = sigf(zf) * cst[r] + sigf(zi) * ftanh(zg);
      float h  = sigf(zo) * ftanh(cn);
      cst[r] = cn;
      hfv[r] = h;
      hb[r] = f2bf(h);
    }
    *(uint2*)(&hbuf[rb ^ 1][s][j0]) = *(const uint2*)hb;
    *(uint2*)(hout + ((size_t)(n0+s)*TT + t)*HD + j0) = *(const uint2*)hb;
    if (t + 1 < TT) {
      #pragma unroll
      for (int g = 0; g < 4; ++g) xv[g] = xvn[g];
    }
    lds_barrier();
  }
  if (hfin) *(float4*)(hfin + (size_t)(n0+s)*128 + j0) = make_float4(hfv[0],hfv[1],hfv[2],hfv[3]);
  if (cfin) *(float4*)(cfin + (size_t)(n0+s)*128 + j0) = make_float4(cst[0],cst[1],cst[2],cst[3]);
}

// ---------------- fused attention + feat assembly ----------------
__global__ __launch_bounds__(256) void k_attn(
    const float* __restrict__ keys,     // [MT][128] f32
    const uint16_t* __restrict__ h1,    // [MT][128] bf16
    const uint16_t* __restrict__ imgb,  // [512] bf16
    uint16_t* __restrict__ feat)        // [MT][896]
{
  __shared__ float ks[64][129];
  __shared__ float ps[4][64];
  const int n = blockIdx.x;
  for (int i = threadIdx.x; i < 64*128; i += 256)
    ks[i >> 7][i & 127] = keys[(size_t)n*8192 + i];
  const int w = threadIdx.x >> 6, l = threadIdx.x & 63;
  uint32_t hd = 0;
  if (n > 0) hd = ((const uint32_t*)(h1 + ((size_t)(n-1)*64 + 63)*128))[l];
  const uint4 iv = ((const uint4*)imgb)[l];
  __syncthreads();
  for (int tt = 0; tt < 16; ++tt) {
    const int t = tt*4 + w;
    const size_t m = (size_t)n*64 + t;
    const uint4* hp = (const uint4*)(h1 + m*128);
    float s = 0.f;
    #pragma unroll
    for (int k = 0; k < 16; ++k) {
      uint4 hv = hp[k];
      s += ks[l][8*k+0]*blo(hv.x) + ks[l][8*k+1]*bhi(hv.x)
         + ks[l][8*k+2]*blo(hv.y) + ks[l][8*k+3]*bhi(hv.y)
         + ks[l][8*k+4]*blo(hv.z) + ks[l][8*k+5]*bhi(hv.z)
         + ks[l][8*k+6]*blo(hv.w) + ks[l][8*k+7]*bhi(hv.w);
    }
    float mx = s;
    #pragma unroll
    for (int o = 32; o; o >>= 1) mx = fmaxf(mx, __shfl_xor(mx, o));
    float p = __expf(s - mx);
    float sm = p;
    #pragma unroll
    for (int o = 32; o; o >>= 1) sm += __shfl_xor(sm, o);
    p /= sm;
    ps[w][l] = p;
    float c0 = 0.f, c1 = 0.f;
    #pragma unroll
    for (int q = 0; q < 64; ++q) {
      float pq = ps[w][q];
      c0 += pq * ks[q][l];
      c1 += pq * ks[q][l + 64];
    }
    uint16_t* fr_ = feat + m*896;
    ((uint32_t*)fr_)[l] = ((const uint32_t*)(h1 + m*128))[l];  // h1 copy
    fr_[128 + l] = f2bf(c0);
    fr_[192 + l] = f2bf(c1);
    ((uint32_t*)(fr_ + 256))[l] = hd;                          // history
    ((uint4*)(fr_ + 384))[l] = iv;                             // img
  }
}

extern "C" void kernel_launch(void* const* d_in, const int* in_sizes, int n_in,
                              void* d_out, int out_size, void* d_ws, size_t ws_size,
                              hipStream_t stream) {
  const int*   questions = (const int*)d_in[0];
  const int*   answers   = (const int*)d_in[1];
  const int*   lens      = (const int*)d_in[2];
  const float* img       = (const float*)d_in[3];
  const float* emb       = (const float*)d_in[4];
  const float* eWih0 = (const float*)d_in[5],  *eWhh0 = (const float*)d_in[6],  *eB0 = (const float*)d_in[7];
  const float* eWih1 = (const float*)d_in[8],  *eWhh1 = (const float*)d_in[9],  *eB1 = (const float*)d_in[10];
  const float* dWih0 = (const float*)d_in[11], *dWhh0 = (const float*)d_in[12], *dB0 = (const float*)d_in[13];
  const float* dWih1 = (const float*)d_in[14], *dWhh1 = (const float*)d_in[15], *dB1 = (const float*)d_in[16];
  const float* Wk   = (const float*)d_in[17], *bk   = (const float*)d_in[18];
  const float* Wout = (const float*)d_in[19], *bout = (const float*)d_in[20];

  char* ws = (char*)d_ws;
  size_t off = 0;
  auto alloc = [&](size_t n)->char* {
    char* p = ws + off; off += (n + 255) & ~(size_t)255; return p;
  };
  uint16_t* embP  = (uint16_t*)alloc((size_t)VD*128*2);
  uint16_t* wih0e = (uint16_t*)alloc(512*128*2);
  uint16_t* whh0e = (uint16_t*)alloc(512*128*2);
  uint16_t* wih1e = (uint16_t*)alloc(512*128*2);
  uint16_t* whh1e = (uint16_t*)alloc(512*128*2);
  uint16_t* wih0d = (uint16_t*)alloc(512*128*2);
  uint16_t* whh0d = (uint16_t*)alloc(512*128*2);
  uint16_t* wih1d = (uint16_t*)alloc(512*128*2);
  uint16_t* whh1d = (uint16_t*)alloc(512*128*2);
  uint16_t* wkb   = (uint16_t*)alloc(128*128*2);
  uint16_t* woutb = (uint16_t*)alloc((size_t)1024*896*2);   // padded to 1024 rows
  uint16_t* imgb  = (uint16_t*)alloc(512*2);
  uint16_t* Xbuf  = (uint16_t*)alloc((size_t)MT*512*2);
  uint16_t* hA    = (uint16_t*)alloc((size_t)MT*128*2);
  uint16_t* h1b   = (uint16_t*)alloc((size_t)MT*128*2);
  float*    keysf = (float*)   alloc((size_t)MT*128*4);
  uint16_t* feat  = (uint16_t*)alloc((size_t)MT*896*2);
  float* eh0 = (float*)alloc(NS*128*4);
  float* ec0 = (float*)alloc(NS*128*4);
  float* eh1 = (float*)alloc(NS*128*4);
  float* ec1 = (float*)alloc(NS*128*4);
  if (off > ws_size) return;  // workspace too small; fail visibly

  ConvJobs jobs;
  jobs.j[0]  = {emb,   embP,  VD,  VD,  ED,  128};
  jobs.j[1]  = {eWih0, wih0e, 512, 512, ED,  128};
  jobs.j[2]  = {eWhh0, whh0e, 512, 512, 128, 128};
  jobs.j[3]  = {eWih1, wih1e, 512, 512, 128, 128};
  jobs.j[4]  = {eWhh1, whh1e, 512, 512, 128, 128};
  jobs.j[5]  = {dWih0, wih0d, 512, 512, ED,  128};
  jobs.j[6]  = {dWhh0, whh0d, 512, 512, 128, 128};
  jobs.j[7]  = {dWih1, wih1d, 512, 512, 128, 128};
  jobs.j[8]  = {dWhh1, whh1d, 512, 512, 128, 128};
  jobs.j[9]  = {Wk,    wkb,   128, 128, 128, 128};
  jobs.j[10] = {Wout,  woutb, 1024, VD, 896, 896};
  jobs.j[11] = {img,   imgb,  1,   1,   512, 512};
  hipLaunchKernelGGL(k_convert, dim3(1024), dim3(256), 0, stream, jobs);

  // ---- encoder ----
  hipLaunchKernelGGL(k_gemm<3>, dim3(4, MT/128), dim3(256), 0, stream, embP, wih0e, eB0, Xbuf, 512, 128, nullptr, questions);
  hipLaunchKernelGGL(k_lstm_mfma, dim3(NS/16), dim3(512), 0, stream, Xbuf, whh0e, (const float*)nullptr, (const float*)nullptr, hA, eh0, ec0);
  hipLaunchKernelGGL(k_gemm<3>, dim3(4, MT/128), dim3(256), 0, stream, hA, wih1e, eB1, Xbuf, 512, 128, nullptr, nullptr);
  hipLaunchKernelGGL(k_lstm_mfma, dim3(NS/16), dim3(512), 0, stream, Xbuf, whh1e, (const float*)nullptr, (const float*)nullptr, h1b, eh1, ec1);
  hipLaunchKernelGGL(k_gemm<0>, dim3(1, MT/128), dim3(256), 0, stream, h1b, wkb, bk, keysf, 128, 128, nullptr, nullptr);

  // ---- decoder ----
  hipLaunchKernelGGL(k_gemm<3>, dim3(4, MT/128), dim3(256), 0, stream, embP, wih0d, dB0, Xbuf, 512, 128, nullptr, answers);
  hipLaunchKernelGGL(k_lstm_mfma, dim3(NS/16), dim3(512), 0, stream, Xbuf, whh0d, eh0, ec0, hA, (float*)nullptr, (float*)nullptr);
  hipLaunchKernelGGL(k_gemm<3>, dim3(4, MT/128), dim3(256), 0, stream, hA, wih1d, dB1, Xbuf, 512, 128, nullptr, nullptr);
  hipLaunchKernelGGL(k_lstm_mfma, dim3(NS/16), dim3(512), 0, stream, Xbuf, whh1d, eh1, ec1, h1b, (float*)nullptr, (float*)nullptr);

  // ---- fused attention/feat + output projection ----
  hipLaunchKernelGGL(k_attn, dim3(NS), dim3(256), 0, stream, keysf, h1b, imgb, feat);
  hipLaunchKernelGGL(k_gemm<2>, dim3(8, MT/128), dim3(256), 0, stream, feat, woutb, bout, d_out, VD, 896, lens, nullptr);
}